// Round 8
// baseline (383.668 us; speedup 1.0000x reference)
//
#include <hip/hip_runtime.h>
#include <math.h>
#include <cstddef>

#define EPS 1e-5f

typedef __attribute__((ext_vector_type(8))) short bf16x8;
typedef __attribute__((ext_vector_type(4))) float f32x4;

__device__ __forceinline__ float wave_sum(float v) {
#pragma unroll
  for (int o = 32; o > 0; o >>= 1) v += __shfl_xor(v, o, 64);
  return v;
}

// fp32 -> bf16 bits, round-to-nearest-even (finite inputs only)
__device__ __forceinline__ unsigned short f2b(float f) {
  union { float f; unsigned int u; } v; v.f = f;
  unsigned int r = (v.u + 0x7FFFu + ((v.u >> 16) & 1u)) >> 16;
  return (unsigned short)r;
}
__device__ __forceinline__ float b2f(unsigned short u) {
  union { unsigned int u; float f; } v; v.u = ((unsigned int)u) << 16;
  return v.f;
}

// ============ Weight pre-conversion: fp32 -> bf16, 8 arrays in one launch ==
struct WConvArgs {
  const float* src[8];
  unsigned short* dst[8];
  int n[8];
};
__global__ __launch_bounds__(256) void conv_w(WConvArgs a) {
  const int arr = blockIdx.y;
  const int i = (blockIdx.x * 256 + threadIdx.x) * 4;
  if (i >= a.n[arr]) return;
  const float4 f = *(const float4*)(a.src[arr] + i);
  unsigned short t[4] = {f2b(f.x), f2b(f.y), f2b(f.z), f2b(f.w)};
  unsigned short* d = a.dst[arr] + i;
  *(ushort2*)d = *(ushort2*)&t[0];
  *(ushort2*)(d + 2) = *(ushort2*)&t[2];
}

__global__ __launch_bounds__(256) void zero_stats(float* __restrict__ st) {
  st[blockIdx.x * 256 + threadIdx.x] = 0.f;
}

// ============ MFMA GEMM: C[M,N] = A[M,K] @ W[N,K]^T + bias =================
// 32x64 tile, 4 waves, double-buffered LDS, 1 barrier/K-step.
// ASRC: 0 = bf16 A; 1 = raw f32 A (convert); 2 = attention 4-way split-merge;
//       3 = LN-apply (f32 z + row stats + affine w,b) during staging;
//       4 = InstanceNorm-apply (f32 z + row stats, no affine).
// WF: (with ASRC 3/4) blocks with n0==0 also write the normalized f32 rows
//     to finW (needed by the residual path downstream).
// STATS: epilogue accumulates per-row sum/sumsq of the stored value into
//        stOut via shuffle-reduce + atomicAdd (consumer derives mean/var).
// RESID: adds Rf before store. SCALEQ: cols [0,512) scaled by 0.125.
template <int RELU, int ASRC, int OUT_F32, int OUT_BF16, int RESID, int SCALEQ,
          int STATS, int WF>
__global__ __launch_bounds__(256) void gemm32(
    const void* __restrict__ Aptr, const float* __restrict__ pmp,
    const float* __restrict__ stA, const float* __restrict__ lnw,
    const float* __restrict__ lnb, const unsigned short* __restrict__ W,
    const float* __restrict__ bias, const float* __restrict__ Rf,
    float* __restrict__ Cf, unsigned short* __restrict__ Cb,
    float* __restrict__ stOut, float* __restrict__ finW,
    int M, int N, int K) {
  __shared__ __align__(16) unsigned short As[2][32][72];
  __shared__ __align__(16) unsigned short Ws[2][64][72];
  const int tid = threadIdx.x;
  const int wid = tid >> 6, lane = tid & 63;
  const int ln = lane & 15, quad = lane >> 4;
  const int m0 = blockIdx.x * 32, n0 = blockIdx.y * 64;
  const int arow = tid >> 3, aseg = tid & 7;   // A: 8 threads/row, 8 elems
  const int wrow = tid >> 2, wseg = tid & 3;   // W: 4 threads/row, 16 elems
  const int KS = K >> 6;

  bf16x8 ra;
  float4 ra32[2];
  float4 rlw[2], rlb[2];
  float rmean, rrs;
  bf16x8 rwb0, rwb1;
  bf16x8 rp[4];
  float rl;
  int curk0 = 0;

  auto load_tile = [&](int ks) {
    const int k0 = ks * 64;
    curk0 = k0;
    if (ASRC == 2) {
      const int h = ks;  // K=512, 8 heads of 64: head index == K-step
      const int row = m0 + arow;
      rl = 0.f;
#pragma unroll
      for (int s = 0; s < 4; ++s) {
        const size_t b = (size_t)((s * 8 + h) * 2048 + row);
        rl += pmp[b];
        rp[s] = *(const bf16x8*)((const unsigned short*)Aptr + b * 64 + aseg * 8);
      }
    } else if (ASRC == 1 || ASRC == 3 || ASRC == 4) {
      const int row = m0 + arow;
      const float* ap = (const float*)Aptr + (size_t)row * K + k0 + aseg * 8;
      ra32[0] = *(const float4*)ap;
      ra32[1] = *(const float4*)(ap + 4);
      if (ASRC == 3 || ASRC == 4) {
        float s = stA[row * 2], q = stA[row * 2 + 1];
        rmean = s * (1.f / 512.f);
        rrs = rsqrtf(q * (1.f / 512.f) - rmean * rmean + EPS);
        if (ASRC == 3) {
          rlw[0] = *(const float4*)(lnw + k0 + aseg * 8);
          rlw[1] = *(const float4*)(lnw + k0 + aseg * 8 + 4);
          rlb[0] = *(const float4*)(lnb + k0 + aseg * 8);
          rlb[1] = *(const float4*)(lnb + k0 + aseg * 8 + 4);
        }
      }
    } else {
      ra = *(const bf16x8*)((const unsigned short*)Aptr +
                            (size_t)(m0 + arow) * K + k0 + aseg * 8);
    }
    const unsigned short* wp = W + (size_t)(n0 + wrow) * K + k0 + wseg * 16;
    rwb0 = *(const bf16x8*)wp;
    rwb1 = *(const bf16x8*)(wp + 8);
  };

  auto store_tile = [&](int buf) {
    if (ASRC == 2) {
      float inv = 1.f / rl;
      unsigned short ta[8];
#pragma unroll
      for (int j = 0; j < 8; ++j) {
        float s = b2f((unsigned short)rp[0][j]) + b2f((unsigned short)rp[1][j]) +
                  b2f((unsigned short)rp[2][j]) + b2f((unsigned short)rp[3][j]);
        ta[j] = f2b(inv * s);
      }
      *(bf16x8*)&As[buf][arow][aseg * 8] = *(const bf16x8*)&ta[0];
    } else if (ASRC == 1 || ASRC == 3 || ASRC == 4) {
      float zv[8] = {ra32[0].x, ra32[0].y, ra32[0].z, ra32[0].w,
                     ra32[1].x, ra32[1].y, ra32[1].z, ra32[1].w};
      float lwv[8], lbv[8];
      if (ASRC == 3) {
        lwv[0] = rlw[0].x; lwv[1] = rlw[0].y; lwv[2] = rlw[0].z; lwv[3] = rlw[0].w;
        lwv[4] = rlw[1].x; lwv[5] = rlw[1].y; lwv[6] = rlw[1].z; lwv[7] = rlw[1].w;
        lbv[0] = rlb[0].x; lbv[1] = rlb[0].y; lbv[2] = rlb[0].z; lbv[3] = rlb[0].w;
        lbv[4] = rlb[1].x; lbv[5] = rlb[1].y; lbv[6] = rlb[1].z; lbv[7] = rlb[1].w;
      }
      float tv[8];
      unsigned short ta[8];
#pragma unroll
      for (int j = 0; j < 8; ++j) {
        float t = zv[j];
        if (ASRC == 3) t = (t - rmean) * rrs * lwv[j] + lbv[j];
        if (ASRC == 4) t = (t - rmean) * rrs;
        tv[j] = t;
        ta[j] = f2b(t);
      }
      *(bf16x8*)&As[buf][arow][aseg * 8] = *(const bf16x8*)&ta[0];
      if (WF) {
        if (n0 == 0) {
          float* fp = finW + (size_t)(m0 + arow) * K + curk0 + aseg * 8;
          float4 o0 = {tv[0], tv[1], tv[2], tv[3]};
          float4 o1 = {tv[4], tv[5], tv[6], tv[7]};
          *(float4*)fp = o0;
          *(float4*)(fp + 4) = o1;
        }
      }
    } else {
      *(bf16x8*)&As[buf][arow][aseg * 8] = ra;
    }
    *(bf16x8*)&Ws[buf][wrow][wseg * 16] = rwb0;
    *(bf16x8*)&Ws[buf][wrow][wseg * 16 + 8] = rwb1;
  };

  f32x4 acc[2];
  acc[0] = (f32x4){0.f, 0.f, 0.f, 0.f};
  acc[1] = (f32x4){0.f, 0.f, 0.f, 0.f};

  const int mrow = (wid & 1) * 16, nh = wid >> 1;

  load_tile(0);
  store_tile(0);
  __syncthreads();

#pragma unroll 1
  for (int ks = 0; ks < KS; ++ks) {
    const int cur = ks & 1;
    if (ks + 1 < KS) load_tile(ks + 1);
#pragma unroll
    for (int kc = 0; kc < 2; ++kc) {
      bf16x8 af = *(const bf16x8*)&As[cur][mrow + ln][kc * 32 + quad * 8];
#pragma unroll
      for (int nt = 0; nt < 2; ++nt) {
        bf16x8 wf = *(const bf16x8*)&Ws[cur][nh * 32 + nt * 16 + ln][kc * 32 + quad * 8];
        acc[nt] = __builtin_amdgcn_mfma_f32_16x16x32_bf16(af, wf, acc[nt], 0, 0, 0);
      }
    }
    if (ks + 1 < KS) store_tile(cur ^ 1);
    __syncthreads();
  }

  const int gm = m0 + mrow + quad * 4;
  const float qs = (SCALEQ && n0 < 512) ? 0.125f : 1.f;
  float vbuf[2][4];
#pragma unroll
  for (int nt = 0; nt < 2; ++nt) {
    const int gn = n0 + nh * 32 + nt * 16 + ln;
    float bv = bias[gn];
#pragma unroll
    for (int r = 0; r < 4; ++r) {
      float v = acc[nt][r] + bv;
      if (SCALEQ) v *= qs;
      if (RELU) v = fmaxf(v, 0.f);
      if (RESID) v += Rf[(size_t)(gm + r) * N + gn];
      vbuf[nt][r] = v;
      if (OUT_F32) Cf[(size_t)(gm + r) * N + gn] = v;
      if (OUT_BF16) Cb[(size_t)(gm + r) * N + gn] = f2b(v);
    }
  }
  if (STATS) {
#pragma unroll
    for (int r = 0; r < 4; ++r) {
      float s = vbuf[0][r] + vbuf[1][r];
      float q = vbuf[0][r] * vbuf[0][r] + vbuf[1][r] * vbuf[1][r];
      s += __shfl_xor(s, 1, 64); q += __shfl_xor(q, 1, 64);
      s += __shfl_xor(s, 2, 64); q += __shfl_xor(q, 2, 64);
      s += __shfl_xor(s, 4, 64); q += __shfl_xor(q, 4, 64);
      s += __shfl_xor(s, 8, 64); q += __shfl_xor(q, 8, 64);
      if (ln == 0) {
        atomicAdd(&stOut[(gm + r) * 2], s);
        atomicAdd(&stOut[(gm + r) * 2 + 1], q);
      }
    }
  }
}

// ============ Flash attention v7: key-split 4, single-buffer LDS ===========
__global__ __launch_bounds__(256) void flash_attn7(
    const unsigned short* __restrict__ qkv, float* __restrict__ pm,
    unsigned short* __restrict__ po) {
  __shared__ __align__(16) unsigned short Ks[64][72];
  __shared__ __align__(16) unsigned short Vt[64][72];
  __shared__ __align__(16) unsigned short Ps[64][72];
  const int qt = blockIdx.x, h = blockIdx.y, sp = blockIdx.z;
  const int tid = threadIdx.x;
  const int wid = tid >> 6, lane = tid & 63;
  const int ln = lane & 15, quad = lane >> 4;
  const int wq0 = wid * 16;

  bf16x8 aq[2];
  {
    const unsigned short* qp =
        qkv + (size_t)(qt * 64 + wq0 + ln) * 1536 + h * 64 + quad * 8;
    aq[0] = *(const bf16x8*)qp;
    aq[1] = *(const bf16x8*)(qp + 32);
  }

  const int key = tid >> 2, seg = tid & 3;  // K staging
  bf16x8 rk0, rk1;
  unsigned short tv[16];

  auto load_kv = [&](int t) {
    const int g = sp * 8 + t;
    const unsigned short* kr =
        qkv + (size_t)(g * 64 + key) * 1536 + 512 + h * 64 + seg * 16;
    rk0 = *(const bf16x8*)kr;
    rk1 = *(const bf16x8*)(kr + 8);
#pragma unroll
    for (int j = 0; j < 16; ++j)
      tv[j] = qkv[(size_t)(g * 64 + wid * 16 + j) * 1536 + 1024 + h * 64 + lane];
  };
  auto store_kv = [&]() {
    *(bf16x8*)&Ks[key][seg * 16] = rk0;
    *(bf16x8*)&Ks[key][seg * 16 + 8] = rk1;
    *(bf16x8*)&Vt[lane][wid * 16] = *(const bf16x8*)&tv[0];
    *(bf16x8*)&Vt[lane][wid * 16 + 8] = *(const bf16x8*)&tv[8];
  };

  float l_r[4] = {0.f, 0.f, 0.f, 0.f};
  f32x4 acc_o[4];
#pragma unroll
  for (int nt = 0; nt < 4; ++nt) acc_o[nt] = (f32x4){0.f, 0.f, 0.f, 0.f};

  load_kv(0);
  store_kv();
  __syncthreads();

#pragma unroll 1
  for (int t = 0; t < 8; ++t) {
    if (t + 1 < 8) load_kv(t + 1);

    f32x4 s_acc[4];
#pragma unroll
    for (int nt = 0; nt < 4; ++nt) s_acc[nt] = (f32x4){0.f, 0.f, 0.f, 0.f};
#pragma unroll
    for (int nt = 0; nt < 4; ++nt) {
      bf16x8 kf0 = *(const bf16x8*)&Ks[nt * 16 + ln][quad * 8];
      bf16x8 kf1 = *(const bf16x8*)&Ks[nt * 16 + ln][32 + quad * 8];
      s_acc[nt] = __builtin_amdgcn_mfma_f32_16x16x32_bf16(aq[0], kf0, s_acc[nt], 0, 0, 0);
      s_acc[nt] = __builtin_amdgcn_mfma_f32_16x16x32_bf16(aq[1], kf1, s_acc[nt], 0, 0, 0);
    }

#pragma unroll
    for (int nt = 0; nt < 4; ++nt) {
#pragma unroll
      for (int r = 0; r < 4; ++r) {
        float p = __expf(s_acc[nt][r]);
        l_r[r] += p;
        Ps[wq0 + quad * 4 + r][nt * 16 + ln] = f2b(p);
      }
    }

#pragma unroll
    for (int kc = 0; kc < 2; ++kc) {
      bf16x8 pf = *(const bf16x8*)&Ps[wq0 + ln][kc * 32 + quad * 8];
#pragma unroll
      for (int nt = 0; nt < 4; ++nt) {
        bf16x8 vf = *(const bf16x8*)&Vt[nt * 16 + ln][kc * 32 + quad * 8];
        acc_o[nt] = __builtin_amdgcn_mfma_f32_16x16x32_bf16(pf, vf, acc_o[nt], 0, 0, 0);
      }
    }
    __syncthreads();
    if (t + 1 < 8) {
      store_kv();
      __syncthreads();
    }
  }

  const size_t base = (size_t)((sp * 8 + h) * 2048 + qt * 64);
#pragma unroll
  for (int r = 0; r < 4; ++r) {
    float l = l_r[r];
    l += __shfl_xor(l, 1, 64);
    l += __shfl_xor(l, 2, 64);
    l += __shfl_xor(l, 4, 64);
    l += __shfl_xor(l, 8, 64);
    const size_t row = base + wq0 + quad * 4 + r;
    if (ln == 0) pm[row] = l;
#pragma unroll
    for (int nt = 0; nt < 4; ++nt)
      po[row * 64 + nt * 16 + ln] = f2b(acc_o[nt][r]);
  }
}

// ============ Tail fusion: apply ln2_3 -> inorm -> +feat0 -> bf16 ==========
// One wave per row: t = ln2(z) from stats; then row-inorm(t) + feat0.
__global__ __launch_bounds__(256) void tail_fuse(
    const float* __restrict__ z, const float* __restrict__ st,
    const float* __restrict__ lnw, const float* __restrict__ lnb,
    const float* __restrict__ feat0, unsigned short* __restrict__ outb) {
  const int row = blockIdx.x * 4 + (threadIdx.x >> 6);
  const int lane = threadIdx.x & 63;
  const float4* zs = (const float4*)(z + (size_t)row * 512);
  float4 a = zs[lane], b = zs[lane + 64];
  const float mu = st[row * 2] * (1.f / 512.f);
  const float rs = rsqrtf(st[row * 2 + 1] * (1.f / 512.f) - mu * mu + EPS);
  float4 wa = ((const float4*)lnw)[lane], wb = ((const float4*)lnw)[lane + 64];
  float4 ba = ((const float4*)lnb)[lane], bb = ((const float4*)lnb)[lane + 64];
  float t[8];
  t[0] = (a.x - mu) * rs * wa.x + ba.x; t[1] = (a.y - mu) * rs * wa.y + ba.y;
  t[2] = (a.z - mu) * rs * wa.z + ba.z; t[3] = (a.w - mu) * rs * wa.w + ba.w;
  t[4] = (b.x - mu) * rs * wb.x + bb.x; t[5] = (b.y - mu) * rs * wb.y + bb.y;
  t[6] = (b.z - mu) * rs * wb.z + bb.z; t[7] = (b.w - mu) * rs * wb.w + bb.w;
  float sum = t[0] + t[1] + t[2] + t[3] + t[4] + t[5] + t[6] + t[7];
  float mean = wave_sum(sum) * (1.f / 512.f);
  float vs = 0.f;
#pragma unroll
  for (int j = 0; j < 8; ++j) vs += (t[j] - mean) * (t[j] - mean);
  float rs2 = rsqrtf(wave_sum(vs) * (1.f / 512.f) + EPS);
  const float4* f0 = (const float4*)(feat0 + (size_t)row * 512);
  float4 za = f0[lane], zb = f0[lane + 64];
  float o[8];
  o[0] = za.x + (t[0] - mean) * rs2; o[1] = za.y + (t[1] - mean) * rs2;
  o[2] = za.z + (t[2] - mean) * rs2; o[3] = za.w + (t[3] - mean) * rs2;
  o[4] = zb.x + (t[4] - mean) * rs2; o[5] = zb.y + (t[5] - mean) * rs2;
  o[6] = zb.z + (t[6] - mean) * rs2; o[7] = zb.w + (t[7] - mean) * rs2;
  unsigned short* dbp = outb + (size_t)row * 512;
  unsigned short t0[4] = {f2b(o[0]), f2b(o[1]), f2b(o[2]), f2b(o[3])};
  unsigned short t1[4] = {f2b(o[4]), f2b(o[5]), f2b(o[6]), f2b(o[7])};
  *(ushort2*)&dbp[lane * 4] = *(ushort2*)&t0[0];
  *(ushort2*)&dbp[lane * 4 + 2] = *(ushort2*)&t0[2];
  *(ushort2*)&dbp[256 + lane * 4] = *(ushort2*)&t1[0];
  *(ushort2*)&dbp[256 + lane * 4 + 2] = *(ushort2*)&t1[2];
}

// dist with fused inorm128: one wave per row
__global__ __launch_bounds__(256) void dist2(const float* __restrict__ fq,
                                             const float* __restrict__ hi,
                                             const float* __restrict__ ne,
                                             float* __restrict__ out) {
  const int row = blockIdx.x * 4 + (threadIdx.x >> 6);
  const int lane = threadIdx.x & 63;
  float f0 = fq[(size_t)row * 128 + lane];
  float f1 = fq[(size_t)row * 128 + 64 + lane];
  float mean = wave_sum(f0 + f1) * (1.f / 128.f);
  float vs = (f0 - mean) * (f0 - mean) + (f1 - mean) * (f1 - mean);
  float rs = rsqrtf(wave_sum(vs) * (1.f / 128.f) + EPS);
  f0 = (f0 - mean) * rs;
  f1 = (f1 - mean) * rs;
  float mp = 1e30f, mn = 1e30f;
  for (int p = 0; p < 40; ++p) {
    float h0 = hi[p * 128 + lane], h1 = hi[p * 128 + 64 + lane];
    float d0 = f0 - h0, d1 = f1 - h1;
    float d2 = wave_sum(d0 * d0 + d1 * d1);
    mp = fminf(mp, d2);
    float n0 = ne[p * 128 + lane], n1 = ne[p * 128 + 64 + lane];
    d0 = f0 - n0; d1 = f1 - n1;
    d2 = wave_sum(d0 * d0 + d1 * d1);
    mn = fminf(mn, d2);
  }
  if (lane == 0) {
    out[row * 2 + 0] = -sqrtf(mn);
    out[row * 2 + 1] = -sqrtf(mp);
  }
}

extern "C" void kernel_launch(void* const* d_in, const int* in_sizes, int n_in,
                              void* d_out, int out_size, void* d_ws, size_t ws_size,
                              hipStream_t stream) {
  const float* x        = (const float*)d_in[0];
  const float* reduce_w = (const float*)d_in[1];
  const float* reduce_b = (const float*)d_in[2];
  const float* in_w     = (const float*)d_in[3];
  const float* in_b     = (const float*)d_in[4];
  const float* out_w    = (const float*)d_in[5];
  const float* out_b    = (const float*)d_in[6];
  const float* ff1_w    = (const float*)d_in[7];
  const float* ff1_b    = (const float*)d_in[8];
  const float* ff2_w    = (const float*)d_in[9];
  const float* ff2_b    = (const float*)d_in[10];
  const float* ln1_w    = (const float*)d_in[11];
  const float* ln1_b    = (const float*)d_in[12];
  const float* ln2_w    = (const float*)d_in[13];
  const float* ln2_b    = (const float*)d_in[14];
  const float* mlp_w1   = (const float*)d_in[15];
  const float* mlp_b1   = (const float*)d_in[16];
  const float* mlp_w2   = (const float*)d_in[17];
  const float* mlp_b2   = (const float*)d_in[18];
  const float* mlp_w3   = (const float*)d_in[19];
  const float* mlp_b3   = (const float*)d_in[20];
  const float* hi       = (const float*)d_in[21];
  const float* ne       = (const float*)d_in[22];
  float* out = (float*)d_out;
  float* ws = (float*)d_ws;

  const size_t MD = (size_t)2048 * 512;  // 1M elems
  float* feat0_f = ws;                // MD : inorm'd reduce output (persists)
  float* fin_f   = ws + MD;           // MD : per-layer ln-applied input (f32)
  float* feat_f  = ws + 2 * MD;       // MD : ln1-applied (f32), resid for ff2
  float* zr      = ws + 3 * MD;       // MD : raw reduce output
  float* zA      = ws + 4 * MD;       // MD : attn-out + resid (pre-ln1)
  float* zB      = ws + 5 * MD;       // MD : ff2 + resid (pre-ln2)
  float* pm      = ws + 6 * MD;       // 65536 : attention l partials
  float* st      = ws + 6 * MD + 65536;  // 7*4096 stats {sum,sumsq}
  unsigned short* u = (unsigned short*)(ws + 6 * MD + 65536 + 7 * 4096);
  unsigned short* qkv_b   = u;            // 3*MD
  unsigned short* relu_b  = u + 3 * MD;   // MD
  unsigned short* mlpin_b = u + 4 * MD;   // MD
  unsigned short* po_b    = u + 5 * MD;   // 4*MD
  unsigned short* relu2_b = qkv_b;        // alias: attention done by then
  float* featq_f = zr;                    // alias: zr dead after layer 1 qkv... (mlp3 is last)

  // bf16 weight region
  unsigned short* wb = u + 9 * MD;
  unsigned short* reduce_wb = wb;                   // 393216
  unsigned short* in_wb     = wb + 393216;          // 2359296
  unsigned short* out_wb    = in_wb + 2359296;      // 786432
  unsigned short* ff1_wb    = out_wb + 786432;      // 786432
  unsigned short* ff2_wb    = ff1_wb + 786432;      // 786432
  unsigned short* mlp_w1b   = ff2_wb + 786432;      // 262144
  unsigned short* mlp_w2b   = mlp_w1b + 262144;     // 262144
  unsigned short* mlp_w3b   = mlp_w2b + 262144;     // 65536

  float* st0  = st;              // reduce out stats
  // per layer i: stA[i] = attn resid stats, stB[i] = ff resid stats
  auto stA = [&](int i) { return st + 4096 * (1 + 2 * i); };
  auto stB = [&](int i) { return st + 4096 * (2 + 2 * i); };

  dim3 blk(256);
  WConvArgs wa;
  wa.src[0] = reduce_w; wa.dst[0] = reduce_wb; wa.n[0] = 393216;
  wa.src[1] = in_w;     wa.dst[1] = in_wb;     wa.n[1] = 2359296;
  wa.src[2] = out_w;    wa.dst[2] = out_wb;    wa.n[2] = 786432;
  wa.src[3] = ff1_w;    wa.dst[3] = ff1_wb;    wa.n[3] = 786432;
  wa.src[4] = ff2_w;    wa.dst[4] = ff2_wb;    wa.n[4] = 786432;
  wa.src[5] = mlp_w1;   wa.dst[5] = mlp_w1b;   wa.n[5] = 262144;
  wa.src[6] = mlp_w2;   wa.dst[6] = mlp_w2b;   wa.n[6] = 262144;
  wa.src[7] = mlp_w3;   wa.dst[7] = mlp_w3b;   wa.n[7] = 65536;
  conv_w<<<dim3(2304, 8), blk, 0, stream>>>(wa);
  zero_stats<<<112, blk, 0, stream>>>(st);

  // reduce: raw f32 A, f32 out + stats
  gemm32<0, 1, 1, 0, 0, 0, 1, 0><<<dim3(64, 8), blk, 0, stream>>>(
      x, nullptr, nullptr, nullptr, nullptr, reduce_wb, reduce_b, nullptr,
      zr, nullptr, st0, nullptr, 2048, 512, 768);

  for (int i = 0; i < 3; ++i) {
    // qkv: A = norm-applied previous output; side-write fin (f32)
    if (i == 0) {
      gemm32<0, 4, 0, 1, 0, 1, 0, 1><<<dim3(64, 24), blk, 0, stream>>>(
          zr, nullptr, st0, nullptr, nullptr, in_wb, in_b,
          nullptr, nullptr, qkv_b, nullptr, feat0_f, 2048, 1536, 512);
    } else {
      gemm32<0, 3, 0, 1, 0, 1, 0, 1><<<dim3(64, 24), blk, 0, stream>>>(
          zB, nullptr, stB(i - 1), ln2_w + (i - 1) * 512, ln2_b + (i - 1) * 512,
          in_wb + (size_t)i * 1536 * 512, in_b + i * 1536,
          nullptr, nullptr, qkv_b, nullptr, fin_f, 2048, 1536, 512);
    }
    flash_attn7<<<dim3(32, 8, 4), blk, 0, stream>>>(qkv_b, pm, po_b);
    const float* resid1 = (i == 0) ? feat0_f : fin_f;
    gemm32<0, 2, 1, 0, 1, 0, 1, 0><<<dim3(64, 8), blk, 0, stream>>>(
        po_b, pm, nullptr, nullptr, nullptr, out_wb + (size_t)i * 512 * 512,
        out_b + i * 512, resid1, zA, nullptr, stA(i), nullptr, 2048, 512, 512);
    // ff1: A = ln1(zA); side-write feat_f; relu
    gemm32<1, 3, 0, 1, 0, 0, 0, 1><<<dim3(64, 8), blk, 0, stream>>>(
        zA, nullptr, stA(i), ln1_w + i * 512, ln1_b + i * 512,
        ff1_wb + (size_t)i * 512 * 512, ff1_b + i * 512,
        nullptr, nullptr, relu_b, nullptr, feat_f, 2048, 512, 512);
    // ff2: + resid feat_f -> zB + stats
    gemm32<0, 0, 1, 0, 1, 0, 1, 0><<<dim3(64, 8), blk, 0, stream>>>(
        relu_b, nullptr, nullptr, nullptr, nullptr,
        ff2_wb + (size_t)i * 512 * 512, ff2_b + i * 512,
        feat_f, zB, nullptr, stB(i), nullptr, 2048, 512, 512);
  }

  tail_fuse<<<512, blk, 0, stream>>>(zB, stB(2), ln2_w + 2 * 512,
                                     ln2_b + 2 * 512, feat0_f, mlpin_b);
  gemm32<1, 0, 0, 1, 0, 0, 0, 0><<<dim3(64, 8), blk, 0, stream>>>(
      mlpin_b, nullptr, nullptr, nullptr, nullptr, mlp_w1b, mlp_b1,
      nullptr, nullptr, relu_b, nullptr, nullptr, 2048, 512, 512);
  gemm32<1, 0, 0, 1, 0, 0, 0, 0><<<dim3(64, 8), blk, 0, stream>>>(
      relu_b, nullptr, nullptr, nullptr, nullptr, mlp_w2b, mlp_b2,
      nullptr, nullptr, relu2_b, nullptr, nullptr, 2048, 512, 512);
  gemm32<0, 0, 1, 0, 0, 0, 0, 0><<<dim3(64, 2), blk, 0, stream>>>(
      relu2_b, nullptr, nullptr, nullptr, nullptr, mlp_w3b, mlp_b3,
      nullptr, featq_f, nullptr, nullptr, nullptr, 2048, 128, 512);
  dist2<<<512, blk, 0, stream>>>(featq_f, hi, ne, out);
}

// Round 9
// 379.066 us; speedup vs baseline: 1.0121x; 1.0121x over previous
//
#include <hip/hip_runtime.h>
#include <math.h>
#include <cstddef>

#define EPS 1e-5f

typedef __attribute__((ext_vector_type(8))) short bf16x8;
typedef __attribute__((ext_vector_type(4))) float f32x4;

__device__ __forceinline__ float wave_sum(float v) {
#pragma unroll
  for (int o = 32; o > 0; o >>= 1) v += __shfl_xor(v, o, 64);
  return v;
}

// fp32 -> bf16 bits, round-to-nearest-even (finite inputs only)
__device__ __forceinline__ unsigned short f2b(float f) {
  union { float f; unsigned int u; } v; v.f = f;
  unsigned int r = (v.u + 0x7FFFu + ((v.u >> 16) & 1u)) >> 16;
  return (unsigned short)r;
}
__device__ __forceinline__ float b2f(unsigned short u) {
  union { unsigned int u; float f; } v; v.u = ((unsigned int)u) << 16;
  return v.f;
}

// ============ Weight pre-conversion: fp32 -> bf16, 8 arrays in one launch ==
struct WConvArgs {
  const float* src[8];
  unsigned short* dst[8];
  int n[8];
};
__global__ __launch_bounds__(256) void conv_w(WConvArgs a) {
  const int arr = blockIdx.y;
  const int i = (blockIdx.x * 256 + threadIdx.x) * 4;
  if (i >= a.n[arr]) return;
  const float4 f = *(const float4*)(a.src[arr] + i);
  unsigned short t[4] = {f2b(f.x), f2b(f.y), f2b(f.z), f2b(f.w)};
  unsigned short* d = a.dst[arr] + i;
  *(ushort2*)d = *(ushort2*)&t[0];
  *(ushort2*)(d + 2) = *(ushort2*)&t[2];
}

// ============ MFMA GEMM: C[M,N] = A[M,K] @ W[N,K]^T + bias =================
// W pre-converted bf16. 32x64 tile, 4 waves. Double-buffered LDS, register
// prefetch, 1 barrier/K-step.
// MERGE: A = attention split-merge: sum of 4 unnormalized partials / sum(l).
// RESID: epilogue adds Rf (residual) before store.
// SCALEQ: multiply columns [0,512) by 0.125 (q scale for attention).
template <int RELU, int AF32, int OUT_F32, int OUT_BF16, int MERGE, int RESID,
          int SCALEQ>
__global__ __launch_bounds__(256) void gemm32(
    const void* __restrict__ Aptr, const float* __restrict__ pmp,
    const unsigned short* __restrict__ W, const float* __restrict__ bias,
    const float* __restrict__ Rf, float* __restrict__ Cf,
    unsigned short* __restrict__ Cb, int M, int N, int K) {
  __shared__ __align__(16) unsigned short As[2][32][72];
  __shared__ __align__(16) unsigned short Ws[2][64][72];
  const int tid = threadIdx.x;
  const int wid = tid >> 6, lane = tid & 63;
  const int ln = lane & 15, quad = lane >> 4;
  const int m0 = blockIdx.x * 32, n0 = blockIdx.y * 64;
  const int arow = tid >> 3, aseg = tid & 7;   // A: 8 threads/row, 8 elems
  const int wrow = tid >> 2, wseg = tid & 3;   // W: 4 threads/row, 16 elems
  const int KS = K >> 6;

  bf16x8 ra;
  float4 ra32[2];
  bf16x8 rwb0, rwb1;
  bf16x8 rp[4];
  float rl;

  auto load_tile = [&](int ks) {
    const int k0 = ks * 64;
    if (MERGE) {
      const int h = ks;  // K=512, 8 heads of 64: head index == K-step
      const int row = m0 + arow;
      rl = 0.f;
#pragma unroll
      for (int s = 0; s < 4; ++s) {
        const size_t b = (size_t)((s * 8 + h) * 2048 + row);
        rl += pmp[b];
        rp[s] = *(const bf16x8*)((const unsigned short*)Aptr + b * 64 + aseg * 8);
      }
    } else if (AF32) {
      const float* ap = (const float*)Aptr + (size_t)(m0 + arow) * K + k0 + aseg * 8;
      ra32[0] = *(const float4*)ap;
      ra32[1] = *(const float4*)(ap + 4);
    } else {
      ra = *(const bf16x8*)((const unsigned short*)Aptr +
                            (size_t)(m0 + arow) * K + k0 + aseg * 8);
    }
    const unsigned short* wp = W + (size_t)(n0 + wrow) * K + k0 + wseg * 16;
    rwb0 = *(const bf16x8*)wp;
    rwb1 = *(const bf16x8*)(wp + 8);
  };

  auto store_tile = [&](int buf) {
    if (MERGE) {
      float inv = 1.f / rl;
      unsigned short ta[8];
#pragma unroll
      for (int j = 0; j < 8; ++j) {
        float s = b2f((unsigned short)rp[0][j]) + b2f((unsigned short)rp[1][j]) +
                  b2f((unsigned short)rp[2][j]) + b2f((unsigned short)rp[3][j]);
        ta[j] = f2b(inv * s);
      }
      *(bf16x8*)&As[buf][arow][aseg * 8] = *(const bf16x8*)&ta[0];
    } else if (AF32) {
      unsigned short ta[8];
      ta[0] = f2b(ra32[0].x); ta[1] = f2b(ra32[0].y);
      ta[2] = f2b(ra32[0].z); ta[3] = f2b(ra32[0].w);
      ta[4] = f2b(ra32[1].x); ta[5] = f2b(ra32[1].y);
      ta[6] = f2b(ra32[1].z); ta[7] = f2b(ra32[1].w);
      *(bf16x8*)&As[buf][arow][aseg * 8] = *(const bf16x8*)&ta[0];
    } else {
      *(bf16x8*)&As[buf][arow][aseg * 8] = ra;
    }
    *(bf16x8*)&Ws[buf][wrow][wseg * 16] = rwb0;
    *(bf16x8*)&Ws[buf][wrow][wseg * 16 + 8] = rwb1;
  };

  f32x4 acc[2];
  acc[0] = (f32x4){0.f, 0.f, 0.f, 0.f};
  acc[1] = (f32x4){0.f, 0.f, 0.f, 0.f};

  const int mrow = (wid & 1) * 16, nh = wid >> 1;

  load_tile(0);
  store_tile(0);
  __syncthreads();

#pragma unroll 1
  for (int ks = 0; ks < KS; ++ks) {
    const int cur = ks & 1;
    if (ks + 1 < KS) load_tile(ks + 1);
#pragma unroll
    for (int kc = 0; kc < 2; ++kc) {
      bf16x8 af = *(const bf16x8*)&As[cur][mrow + ln][kc * 32 + quad * 8];
#pragma unroll
      for (int nt = 0; nt < 2; ++nt) {
        bf16x8 wf = *(const bf16x8*)&Ws[cur][nh * 32 + nt * 16 + ln][kc * 32 + quad * 8];
        acc[nt] = __builtin_amdgcn_mfma_f32_16x16x32_bf16(af, wf, acc[nt], 0, 0, 0);
      }
    }
    if (ks + 1 < KS) store_tile(cur ^ 1);
    __syncthreads();
  }

  const int gm = m0 + mrow + quad * 4;
  const float qs = (SCALEQ && n0 < 512) ? 0.125f : 1.f;
#pragma unroll
  for (int nt = 0; nt < 2; ++nt) {
    const int gn = n0 + nh * 32 + nt * 16 + ln;
    float bv = bias[gn];
#pragma unroll
    for (int r = 0; r < 4; ++r) {
      float v = acc[nt][r] + bv;
      if (SCALEQ) v *= qs;
      if (RELU) v = fmaxf(v, 0.f);
      if (RESID) v += Rf[(size_t)(gm + r) * N + gn];
      if (OUT_F32) Cf[(size_t)(gm + r) * N + gn] = v;
      if (OUT_BF16) Cb[(size_t)(gm + r) * N + gn] = f2b(v);
    }
  }
}

// ============ Flash attention v8: key-split 4, DOUBLE-buffered K/V =========
// grid (32 q-tiles, 8 heads, 4 splits) = 1024 blocks; LDS 46 KB -> 3
// resident blocks/CU. One barrier per K-tile: compute on buf cur while the
// next tile's global loads land; store into cur^1 after compute; barrier.
// No-max softmax (q pre-scaled by 1/8 in qkv GEMM). Partials: l -> pm,
// unnormalized O (bf16) -> po; 4-way merge fused into attn-out GEMM.
__global__ __launch_bounds__(256) void flash_attn8(
    const unsigned short* __restrict__ qkv, float* __restrict__ pm,
    unsigned short* __restrict__ po) {
  __shared__ __align__(16) unsigned short Ks[2][64][72];
  __shared__ __align__(16) unsigned short Vt[2][64][72];
  __shared__ __align__(16) unsigned short Ps[64][72];
  const int qt = blockIdx.x, h = blockIdx.y, sp = blockIdx.z;
  const int tid = threadIdx.x;
  const int wid = tid >> 6, lane = tid & 63;
  const int ln = lane & 15, quad = lane >> 4;
  const int wq0 = wid * 16;

  bf16x8 aq[2];
  {
    const unsigned short* qp =
        qkv + (size_t)(qt * 64 + wq0 + ln) * 1536 + h * 64 + quad * 8;
    aq[0] = *(const bf16x8*)qp;
    aq[1] = *(const bf16x8*)(qp + 32);
  }

  const int key = tid >> 2, seg = tid & 3;  // K staging
  bf16x8 rk0, rk1;
  unsigned short tv[16];

  auto load_kv = [&](int t) {
    const int g = sp * 8 + t;
    const unsigned short* kr =
        qkv + (size_t)(g * 64 + key) * 1536 + 512 + h * 64 + seg * 16;
    rk0 = *(const bf16x8*)kr;
    rk1 = *(const bf16x8*)(kr + 8);
#pragma unroll
    for (int j = 0; j < 16; ++j)
      tv[j] = qkv[(size_t)(g * 64 + wid * 16 + j) * 1536 + 1024 + h * 64 + lane];
  };
  auto store_kv = [&](int buf) {
    *(bf16x8*)&Ks[buf][key][seg * 16] = rk0;
    *(bf16x8*)&Ks[buf][key][seg * 16 + 8] = rk1;
    *(bf16x8*)&Vt[buf][lane][wid * 16] = *(const bf16x8*)&tv[0];
    *(bf16x8*)&Vt[buf][lane][wid * 16 + 8] = *(const bf16x8*)&tv[8];
  };

  float l_r[4] = {0.f, 0.f, 0.f, 0.f};
  f32x4 acc_o[4];
#pragma unroll
  for (int nt = 0; nt < 4; ++nt) acc_o[nt] = (f32x4){0.f, 0.f, 0.f, 0.f};

  load_kv(0);
  store_kv(0);
  __syncthreads();

#pragma unroll 1
  for (int t = 0; t < 8; ++t) {
    const int cur = t & 1;
    if (t + 1 < 8) load_kv(t + 1);  // global loads overlap this tile's math

    f32x4 s_acc[4];
#pragma unroll
    for (int nt = 0; nt < 4; ++nt) s_acc[nt] = (f32x4){0.f, 0.f, 0.f, 0.f};
#pragma unroll
    for (int nt = 0; nt < 4; ++nt) {
      bf16x8 kf0 = *(const bf16x8*)&Ks[cur][nt * 16 + ln][quad * 8];
      bf16x8 kf1 = *(const bf16x8*)&Ks[cur][nt * 16 + ln][32 + quad * 8];
      s_acc[nt] = __builtin_amdgcn_mfma_f32_16x16x32_bf16(aq[0], kf0, s_acc[nt], 0, 0, 0);
      s_acc[nt] = __builtin_amdgcn_mfma_f32_16x16x32_bf16(aq[1], kf1, s_acc[nt], 0, 0, 0);
    }

    // p = exp(s); lane-local l; P -> LDS (wave-local rows, no barrier needed)
#pragma unroll
    for (int nt = 0; nt < 4; ++nt) {
#pragma unroll
      for (int r = 0; r < 4; ++r) {
        float p = __expf(s_acc[nt][r]);
        l_r[r] += p;
        Ps[wq0 + quad * 4 + r][nt * 16 + ln] = f2b(p);
      }
    }

#pragma unroll
    for (int kc = 0; kc < 2; ++kc) {
      bf16x8 pf = *(const bf16x8*)&Ps[wq0 + ln][kc * 32 + quad * 8];
#pragma unroll
      for (int nt = 0; nt < 4; ++nt) {
        bf16x8 vf = *(const bf16x8*)&Vt[cur][nt * 16 + ln][kc * 32 + quad * 8];
        acc_o[nt] = __builtin_amdgcn_mfma_f32_16x16x32_bf16(pf, vf, acc_o[nt], 0, 0, 0);
      }
    }
    if (t + 1 < 8) store_kv(cur ^ 1);  // other buffer: safe during/after compute
    __syncthreads();                    // one barrier per tile
  }

  // epilogue: reduce l across the 16 quad lanes once; write partials
  const size_t base = (size_t)((sp * 8 + h) * 2048 + qt * 64);
#pragma unroll
  for (int r = 0; r < 4; ++r) {
    float l = l_r[r];
    l += __shfl_xor(l, 1, 64);
    l += __shfl_xor(l, 2, 64);
    l += __shfl_xor(l, 4, 64);
    l += __shfl_xor(l, 8, 64);
    const size_t row = base + wq0 + quad * 4 + r;
    if (ln == 0) pm[row] = l;
#pragma unroll
    for (int nt = 0; nt < 4; ++nt)
      po[row * 64 + nt * 16 + ln] = f2b(acc_o[nt][r]);
  }
}

// ============ Row-wise kernels (one wave per row of 2048) ==================
__global__ __launch_bounds__(256) void inorm512(float* __restrict__ dst,
                                                unsigned short* __restrict__ dstb,
                                                const float* __restrict__ src) {
  const int row = blockIdx.x * 4 + (threadIdx.x >> 6);
  const int lane = threadIdx.x & 63;
  const float4* s = (const float4*)(src + (size_t)row * 512);
  float4 a = s[lane], b = s[lane + 64];
  float sum = a.x + a.y + a.z + a.w + b.x + b.y + b.z + b.w;
  float mean = wave_sum(sum) * (1.f / 512.f);
  float vs = (a.x - mean) * (a.x - mean) + (a.y - mean) * (a.y - mean) +
             (a.z - mean) * (a.z - mean) + (a.w - mean) * (a.w - mean) +
             (b.x - mean) * (b.x - mean) + (b.y - mean) * (b.y - mean) +
             (b.z - mean) * (b.z - mean) + (b.w - mean) * (b.w - mean);
  float rs = rsqrtf(wave_sum(vs) * (1.f / 512.f) + EPS);
  float4 oa, obv;
  oa.x = (a.x - mean) * rs; oa.y = (a.y - mean) * rs;
  oa.z = (a.z - mean) * rs; oa.w = (a.w - mean) * rs;
  obv.x = (b.x - mean) * rs; obv.y = (b.y - mean) * rs;
  obv.z = (b.z - mean) * rs; obv.w = (b.w - mean) * rs;
  float4* d = (float4*)(dst + (size_t)row * 512);
  d[lane] = oa; d[lane + 64] = obv;
  unsigned short* db = dstb + (size_t)row * 512;
  unsigned short t0[4] = {f2b(oa.x), f2b(oa.y), f2b(oa.z), f2b(oa.w)};
  unsigned short t1[4] = {f2b(obv.x), f2b(obv.y), f2b(obv.z), f2b(obv.w)};
  *(ushort2*)&db[lane * 4] = *(ushort2*)&t0[0];
  *(ushort2*)&db[lane * 4 + 2] = *(ushort2*)&t0[2];
  *(ushort2*)&db[256 + lane * 4] = *(ushort2*)&t1[0];
  *(ushort2*)&db[256 + lane * 4 + 2] = *(ushort2*)&t1[2];
}

// LN over rows of src (already residual-summed); writes f32 + bf16
__global__ __launch_bounds__(256) void ln_res2(float* __restrict__ dst,
                                               unsigned short* __restrict__ dstb,
                                               const float* __restrict__ src,
                                               const float* __restrict__ w,
                                               const float* __restrict__ bb) {
  const int row = blockIdx.x * 4 + (threadIdx.x >> 6);
  const int lane = threadIdx.x & 63;
  const float4* xs = (const float4*)(src + (size_t)row * 512);
  float4 a = xs[lane], b = xs[lane + 64];
  float sum = a.x + a.y + a.z + a.w + b.x + b.y + b.z + b.w;
  float mean = wave_sum(sum) * (1.f / 512.f);
  float vs = (a.x - mean) * (a.x - mean) + (a.y - mean) * (a.y - mean) +
             (a.z - mean) * (a.z - mean) + (a.w - mean) * (a.w - mean) +
             (b.x - mean) * (b.x - mean) + (b.y - mean) * (b.y - mean) +
             (b.z - mean) * (b.z - mean) + (b.w - mean) * (b.w - mean);
  float rs = rsqrtf(wave_sum(vs) * (1.f / 512.f) + EPS);
  float4 wa = ((const float4*)w)[lane], wb = ((const float4*)w)[lane + 64];
  float4 ba = ((const float4*)bb)[lane], bbv = ((const float4*)bb)[lane + 64];
  float4 oa, ob2;
  oa.x = (a.x - mean) * rs * wa.x + ba.x; oa.y = (a.y - mean) * rs * wa.y + ba.y;
  oa.z = (a.z - mean) * rs * wa.z + ba.z; oa.w = (a.w - mean) * rs * wa.w + ba.w;
  ob2.x = (b.x - mean) * rs * wb.x + bbv.x; ob2.y = (b.y - mean) * rs * wb.y + bbv.y;
  ob2.z = (b.z - mean) * rs * wb.z + bbv.z; ob2.w = (b.w - mean) * rs * wb.w + bbv.w;
  float4* d = (float4*)(dst + (size_t)row * 512);
  d[lane] = oa; d[lane + 64] = ob2;
  unsigned short* dbp = dstb + (size_t)row * 512;
  unsigned short t0[4] = {f2b(oa.x), f2b(oa.y), f2b(oa.z), f2b(oa.w)};
  unsigned short t1[4] = {f2b(ob2.x), f2b(ob2.y), f2b(ob2.z), f2b(ob2.w)};
  *(ushort2*)&dbp[lane * 4] = *(ushort2*)&t0[0];
  *(ushort2*)&dbp[lane * 4 + 2] = *(ushort2*)&t0[2];
  *(ushort2*)&dbp[256 + lane * 4] = *(ushort2*)&t1[0];
  *(ushort2*)&dbp[256 + lane * 4 + 2] = *(ushort2*)&t1[2];
}

__global__ __launch_bounds__(256) void add_inorm(float* __restrict__ feat,
                                                 unsigned short* __restrict__ featb,
                                                 const float* __restrict__ feat0) {
  const int row = blockIdx.x * 4 + (threadIdx.x >> 6);
  const int lane = threadIdx.x & 63;
  float4* f = (float4*)(feat + (size_t)row * 512);
  const float4* f0 = (const float4*)(feat0 + (size_t)row * 512);
  float4 a = f[lane], b = f[lane + 64];
  float sum = a.x + a.y + a.z + a.w + b.x + b.y + b.z + b.w;
  float mean = wave_sum(sum) * (1.f / 512.f);
  float vs = (a.x - mean) * (a.x - mean) + (a.y - mean) * (a.y - mean) +
             (a.z - mean) * (a.z - mean) + (a.w - mean) * (a.w - mean) +
             (b.x - mean) * (b.x - mean) + (b.y - mean) * (b.y - mean) +
             (b.z - mean) * (b.z - mean) + (b.w - mean) * (b.w - mean);
  float rs = rsqrtf(wave_sum(vs) * (1.f / 512.f) + EPS);
  float4 za = f0[lane], zb = f0[lane + 64];
  float4 oa, ob2;
  oa.x = za.x + (a.x - mean) * rs; oa.y = za.y + (a.y - mean) * rs;
  oa.z = za.z + (a.z - mean) * rs; oa.w = za.w + (a.w - mean) * rs;
  ob2.x = zb.x + (b.x - mean) * rs; ob2.y = zb.y + (b.y - mean) * rs;
  ob2.z = zb.z + (b.z - mean) * rs; ob2.w = zb.w + (b.w - mean) * rs;
  f[lane] = oa; f[lane + 64] = ob2;
  unsigned short* dbp = featb + (size_t)row * 512;
  unsigned short t0[4] = {f2b(oa.x), f2b(oa.y), f2b(oa.z), f2b(oa.w)};
  unsigned short t1[4] = {f2b(ob2.x), f2b(ob2.y), f2b(ob2.z), f2b(ob2.w)};
  *(ushort2*)&dbp[lane * 4] = *(ushort2*)&t0[0];
  *(ushort2*)&dbp[lane * 4 + 2] = *(ushort2*)&t0[2];
  *(ushort2*)&dbp[256 + lane * 4] = *(ushort2*)&t1[0];
  *(ushort2*)&dbp[256 + lane * 4 + 2] = *(ushort2*)&t1[2];
}

// dist with fused inorm128: one wave per row
__global__ __launch_bounds__(256) void dist2(const float* __restrict__ fq,
                                             const float* __restrict__ hi,
                                             const float* __restrict__ ne,
                                             float* __restrict__ out) {
  const int row = blockIdx.x * 4 + (threadIdx.x >> 6);
  const int lane = threadIdx.x & 63;
  float f0 = fq[(size_t)row * 128 + lane];
  float f1 = fq[(size_t)row * 128 + 64 + lane];
  float mean = wave_sum(f0 + f1) * (1.f / 128.f);
  float vs = (f0 - mean) * (f0 - mean) + (f1 - mean) * (f1 - mean);
  float rs = rsqrtf(wave_sum(vs) * (1.f / 128.f) + EPS);
  f0 = (f0 - mean) * rs;
  f1 = (f1 - mean) * rs;
  float mp = 1e30f, mn = 1e30f;
  for (int p = 0; p < 40; ++p) {
    float h0 = hi[p * 128 + lane], h1 = hi[p * 128 + 64 + lane];
    float d0 = f0 - h0, d1 = f1 - h1;
    float d2 = wave_sum(d0 * d0 + d1 * d1);
    mp = fminf(mp, d2);
    float n0 = ne[p * 128 + lane], n1 = ne[p * 128 + 64 + lane];
    d0 = f0 - n0; d1 = f1 - n1;
    d2 = wave_sum(d0 * d0 + d1 * d1);
    mn = fminf(mn, d2);
  }
  if (lane == 0) {
    out[row * 2 + 0] = -sqrtf(mn);
    out[row * 2 + 1] = -sqrtf(mp);
  }
}

extern "C" void kernel_launch(void* const* d_in, const int* in_sizes, int n_in,
                              void* d_out, int out_size, void* d_ws, size_t ws_size,
                              hipStream_t stream) {
  const float* x        = (const float*)d_in[0];
  const float* reduce_w = (const float*)d_in[1];
  const float* reduce_b = (const float*)d_in[2];
  const float* in_w     = (const float*)d_in[3];
  const float* in_b     = (const float*)d_in[4];
  const float* out_w    = (const float*)d_in[5];
  const float* out_b    = (const float*)d_in[6];
  const float* ff1_w    = (const float*)d_in[7];
  const float* ff1_b    = (const float*)d_in[8];
  const float* ff2_w    = (const float*)d_in[9];
  const float* ff2_b    = (const float*)d_in[10];
  const float* ln1_w    = (const float*)d_in[11];
  const float* ln1_b    = (const float*)d_in[12];
  const float* ln2_w    = (const float*)d_in[13];
  const float* ln2_b    = (const float*)d_in[14];
  const float* mlp_w1   = (const float*)d_in[15];
  const float* mlp_b1   = (const float*)d_in[16];
  const float* mlp_w2   = (const float*)d_in[17];
  const float* mlp_b2   = (const float*)d_in[18];
  const float* mlp_w3   = (const float*)d_in[19];
  const float* mlp_b3   = (const float*)d_in[20];
  const float* hi       = (const float*)d_in[21];
  const float* ne       = (const float*)d_in[22];
  float* out = (float*)d_out;
  float* ws = (float*)d_ws;

  const size_t MD = (size_t)2048 * 512;  // 1M elems
  float* feat0_f = ws;                // MD
  float* feat_f  = ws + MD;           // MD
  float* tmp_f   = ws + 2 * MD;       // MD
  float* pm      = ws + 3 * MD;       // 4*8*2048 = 65536 f32
  unsigned short* u = (unsigned short*)(ws + 3 * MD + 65536);
  unsigned short* qkv_b   = u;            // 3*MD
  unsigned short* feat0_b = u + 3 * MD;   // MD
  unsigned short* feat_b  = u + 4 * MD;   // MD
  unsigned short* relu_b  = u + 5 * MD;   // MD
  unsigned short* po_b    = u + 6 * MD;   // 4*8*2048*64 = 4*MD
  unsigned short* relu2_b = qkv_b;        // alias: attention done by then
  float* featq_f = tmp_f;

  // bf16 weight region
  unsigned short* wb = u + 10 * MD;
  unsigned short* reduce_wb = wb;                   // 393216
  unsigned short* in_wb     = wb + 393216;          // 2359296
  unsigned short* out_wb    = in_wb + 2359296;      // 786432
  unsigned short* ff1_wb    = out_wb + 786432;      // 786432
  unsigned short* ff2_wb    = ff1_wb + 786432;      // 786432
  unsigned short* mlp_w1b   = ff2_wb + 786432;      // 262144
  unsigned short* mlp_w2b   = mlp_w1b + 262144;     // 262144
  unsigned short* mlp_w3b   = mlp_w2b + 262144;     // 65536

  dim3 blk(256);
  WConvArgs wa;
  wa.src[0] = reduce_w; wa.dst[0] = reduce_wb; wa.n[0] = 393216;
  wa.src[1] = in_w;     wa.dst[1] = in_wb;     wa.n[1] = 2359296;
  wa.src[2] = out_w;    wa.dst[2] = out_wb;    wa.n[2] = 786432;
  wa.src[3] = ff1_w;    wa.dst[3] = ff1_wb;    wa.n[3] = 786432;
  wa.src[4] = ff2_w;    wa.dst[4] = ff2_wb;    wa.n[4] = 786432;
  wa.src[5] = mlp_w1;   wa.dst[5] = mlp_w1b;   wa.n[5] = 262144;
  wa.src[6] = mlp_w2;   wa.dst[6] = mlp_w2b;   wa.n[6] = 262144;
  wa.src[7] = mlp_w3;   wa.dst[7] = mlp_w3b;   wa.n[7] = 65536;
  conv_w<<<dim3(2304, 8), blk, 0, stream>>>(wa);

  gemm32<0, 1, 1, 0, 0, 0, 0><<<dim3(64, 8), blk, 0, stream>>>(
      x, nullptr, reduce_wb, reduce_b, nullptr, feat0_f, nullptr, 2048, 512, 768);
  inorm512<<<512, blk, 0, stream>>>(feat0_f, feat0_b, feat0_f);

  for (int i = 0; i < 3; ++i) {
    const float* fin_f = (i == 0) ? feat0_f : feat_f;
    const unsigned short* fin_b = (i == 0) ? feat0_b : feat_b;
    gemm32<0, 0, 0, 1, 0, 0, 1><<<dim3(64, 24), blk, 0, stream>>>(
        fin_b, nullptr, in_wb + (size_t)i * 1536 * 512, in_b + i * 1536,
        nullptr, nullptr, qkv_b, 2048, 1536, 512);
    flash_attn8<<<dim3(32, 8, 4), blk, 0, stream>>>(qkv_b, pm, po_b);
    gemm32<0, 0, 1, 0, 1, 1, 0><<<dim3(64, 8), blk, 0, stream>>>(
        po_b, pm, out_wb + (size_t)i * 512 * 512, out_b + i * 512,
        fin_f, tmp_f, nullptr, 2048, 512, 512);
    ln_res2<<<512, blk, 0, stream>>>(feat_f, feat_b, tmp_f,
                                     ln1_w + i * 512, ln1_b + i * 512);
    gemm32<1, 0, 0, 1, 0, 0, 0><<<dim3(64, 8), blk, 0, stream>>>(
        feat_b, nullptr, ff1_wb + (size_t)i * 512 * 512, ff1_b + i * 512,
        nullptr, nullptr, relu_b, 2048, 512, 512);
    gemm32<0, 0, 1, 0, 0, 1, 0><<<dim3(64, 8), blk, 0, stream>>>(
        relu_b, nullptr, ff2_wb + (size_t)i * 512 * 512, ff2_b + i * 512,
        feat_f, tmp_f, nullptr, 2048, 512, 512);
    ln_res2<<<512, blk, 0, stream>>>(feat_f, feat_b, tmp_f,
                                     ln2_w + i * 512, ln2_b + i * 512);
  }

  add_inorm<<<512, blk, 0, stream>>>(feat_f, feat_b, feat0_f);
  gemm32<1, 0, 0, 1, 0, 0, 0><<<dim3(64, 8), blk, 0, stream>>>(
      feat_b, nullptr, mlp_w1b, mlp_b1, nullptr, nullptr, relu_b, 2048, 512, 512);
  gemm32<1, 0, 0, 1, 0, 0, 0><<<dim3(64, 8), blk, 0, stream>>>(
      relu_b, nullptr, mlp_w2b, mlp_b2, nullptr, nullptr, relu2_b, 2048, 512, 512);
  gemm32<0, 0, 1, 0, 0, 0, 0><<<dim3(64, 2), blk, 0, stream>>>(
      relu2_b, nullptr, mlp_w3b, mlp_b3, nullptr, featq_f, nullptr, 2048, 128, 512);
  dist2<<<512, blk, 0, stream>>>(featq_f, hi, ne, out);
}

// Round 10
// 366.071 us; speedup vs baseline: 1.0481x; 1.0355x over previous
//
#include <hip/hip_runtime.h>
#include <hip/hip_bf16.h>
#include <math.h>
#include <cstddef>

#define EPS 1e-5f

typedef __attribute__((ext_vector_type(8))) short bf16x8;
typedef __attribute__((ext_vector_type(4))) float f32x4;

__device__ __forceinline__ float wave_sum(float v) {
#pragma unroll
  for (int o = 32; o > 0; o >>= 1) v += __shfl_xor(v, o, 64);
  return v;
}

// fp32 -> bf16 bits, round-to-nearest-even (finite inputs only)
__device__ __forceinline__ unsigned short f2b(float f) {
  union { float f; unsigned int u; } v; v.f = f;
  unsigned int r = (v.u + 0x7FFFu + ((v.u >> 16) & 1u)) >> 16;
  return (unsigned short)r;
}
__device__ __forceinline__ float b2f(unsigned short u) {
  union { unsigned int u; float f; } v; v.u = ((unsigned int)u) << 16;
  return v.f;
}
// packed pair convert (RNE) — lets the compiler use gfx950 packed cvt
__device__ __forceinline__ ushort2 pk2b(float a, float b) {
  __hip_bfloat162 h = __float22bfloat162_rn(make_float2(a, b));
  union { __hip_bfloat162 h; ushort2 u; } v;
  v.h = h;
  return v.u;
}

// ============ Weight pre-conversion: fp32 -> bf16, 8 arrays in one launch ==
struct WConvArgs {
  const float* src[8];
  unsigned short* dst[8];
  int n[8];
};
__global__ __launch_bounds__(256) void conv_w(WConvArgs a) {
  const int arr = blockIdx.y;
  const int i = (blockIdx.x * 256 + threadIdx.x) * 4;
  if (i >= a.n[arr]) return;
  const float4 f = *(const float4*)(a.src[arr] + i);
  unsigned short* d = a.dst[arr] + i;
  *(ushort2*)d = pk2b(f.x, f.y);
  *(ushort2*)(d + 2) = pk2b(f.z, f.w);
}

// ============ MFMA GEMM: C[M,N] = A[M,K] @ W[N,K]^T + bias =================
// W pre-converted bf16. 32x64 tile, 4 waves. Double-buffered LDS, register
// prefetch, 1 barrier/K-step.
// MERGE: A = attention split-merge: sum of 4 unnormalized partials / sum(l).
// RESID: epilogue adds Rf (residual) before store.
// SCALEQ: multiply columns [0,512) by 0.125 (q scale for attention).
template <int RELU, int AF32, int OUT_F32, int OUT_BF16, int MERGE, int RESID,
          int SCALEQ>
__global__ __launch_bounds__(256) void gemm32(
    const void* __restrict__ Aptr, const float* __restrict__ pmp,
    const unsigned short* __restrict__ W, const float* __restrict__ bias,
    const float* __restrict__ Rf, float* __restrict__ Cf,
    unsigned short* __restrict__ Cb, int M, int N, int K) {
  __shared__ __align__(16) unsigned short As[2][32][72];
  __shared__ __align__(16) unsigned short Ws[2][64][72];
  const int tid = threadIdx.x;
  const int wid = tid >> 6, lane = tid & 63;
  const int ln = lane & 15, quad = lane >> 4;
  const int m0 = blockIdx.x * 32, n0 = blockIdx.y * 64;
  const int arow = tid >> 3, aseg = tid & 7;   // A: 8 threads/row, 8 elems
  const int wrow = tid >> 2, wseg = tid & 3;   // W: 4 threads/row, 16 elems
  const int KS = K >> 6;

  bf16x8 ra;
  float4 ra32[2];
  bf16x8 rwb0, rwb1;
  bf16x8 rp[4];
  float rl;

  auto load_tile = [&](int ks) {
    const int k0 = ks * 64;
    if (MERGE) {
      const int h = ks;  // K=512, 8 heads of 64: head index == K-step
      const int row = m0 + arow;
      rl = 0.f;
#pragma unroll
      for (int s = 0; s < 4; ++s) {
        const size_t b = (size_t)((s * 8 + h) * 2048 + row);
        rl += pmp[b];
        rp[s] = *(const bf16x8*)((const unsigned short*)Aptr + b * 64 + aseg * 8);
      }
    } else if (AF32) {
      const float* ap = (const float*)Aptr + (size_t)(m0 + arow) * K + k0 + aseg * 8;
      ra32[0] = *(const float4*)ap;
      ra32[1] = *(const float4*)(ap + 4);
    } else {
      ra = *(const bf16x8*)((const unsigned short*)Aptr +
                            (size_t)(m0 + arow) * K + k0 + aseg * 8);
    }
    const unsigned short* wp = W + (size_t)(n0 + wrow) * K + k0 + wseg * 16;
    rwb0 = *(const bf16x8*)wp;
    rwb1 = *(const bf16x8*)(wp + 8);
  };

  auto store_tile = [&](int buf) {
    if (MERGE) {
      float inv = 1.f / rl;
      unsigned short ta[8];
#pragma unroll
      for (int j = 0; j < 8; j += 2) {
        float s0 = b2f((unsigned short)rp[0][j]) + b2f((unsigned short)rp[1][j]) +
                   b2f((unsigned short)rp[2][j]) + b2f((unsigned short)rp[3][j]);
        float s1 = b2f((unsigned short)rp[0][j + 1]) + b2f((unsigned short)rp[1][j + 1]) +
                   b2f((unsigned short)rp[2][j + 1]) + b2f((unsigned short)rp[3][j + 1]);
        *(ushort2*)&ta[j] = pk2b(inv * s0, inv * s1);
      }
      *(bf16x8*)&As[buf][arow][aseg * 8] = *(const bf16x8*)&ta[0];
    } else if (AF32) {
      unsigned short ta[8];
      *(ushort2*)&ta[0] = pk2b(ra32[0].x, ra32[0].y);
      *(ushort2*)&ta[2] = pk2b(ra32[0].z, ra32[0].w);
      *(ushort2*)&ta[4] = pk2b(ra32[1].x, ra32[1].y);
      *(ushort2*)&ta[6] = pk2b(ra32[1].z, ra32[1].w);
      *(bf16x8*)&As[buf][arow][aseg * 8] = *(const bf16x8*)&ta[0];
    } else {
      *(bf16x8*)&As[buf][arow][aseg * 8] = ra;
    }
    *(bf16x8*)&Ws[buf][wrow][wseg * 16] = rwb0;
    *(bf16x8*)&Ws[buf][wrow][wseg * 16 + 8] = rwb1;
  };

  f32x4 acc[2];
  acc[0] = (f32x4){0.f, 0.f, 0.f, 0.f};
  acc[1] = (f32x4){0.f, 0.f, 0.f, 0.f};

  const int mrow = (wid & 1) * 16, nh = wid >> 1;

  load_tile(0);
  store_tile(0);
  __syncthreads();

#pragma unroll 1
  for (int ks = 0; ks < KS; ++ks) {
    const int cur = ks & 1;
    if (ks + 1 < KS) load_tile(ks + 1);
#pragma unroll
    for (int kc = 0; kc < 2; ++kc) {
      bf16x8 af = *(const bf16x8*)&As[cur][mrow + ln][kc * 32 + quad * 8];
#pragma unroll
      for (int nt = 0; nt < 2; ++nt) {
        bf16x8 wf = *(const bf16x8*)&Ws[cur][nh * 32 + nt * 16 + ln][kc * 32 + quad * 8];
        acc[nt] = __builtin_amdgcn_mfma_f32_16x16x32_bf16(af, wf, acc[nt], 0, 0, 0);
      }
    }
    if (ks + 1 < KS) store_tile(cur ^ 1);
    __syncthreads();
  }

  const int gm = m0 + mrow + quad * 4;
  const float qs = (SCALEQ && n0 < 512) ? 0.125f : 1.f;
#pragma unroll
  for (int nt = 0; nt < 2; ++nt) {
    const int gn = n0 + nh * 32 + nt * 16 + ln;
    float bv = bias[gn];
#pragma unroll
    for (int r = 0; r < 4; ++r) {
      float v = acc[nt][r] + bv;
      if (SCALEQ) v *= qs;
      if (RELU) v = fmaxf(v, 0.f);
      if (RESID) v += Rf[(size_t)(gm + r) * N + gn];
      if (OUT_F32) Cf[(size_t)(gm + r) * N + gn] = v;
      if (OUT_BF16) Cb[(size_t)(gm + r) * N + gn] = f2b(v);
    }
  }
}

// ============ Flash attention v9: key-split 4, single-buffer LDS ===========
// r7 structure (365 us) + l-via-MFMA: l = P @ ones computed by an extra MFMA
// with a register-splat ones B-fragment (no LDS read, no VALU accumulation,
// no epilogue shuffle reduction). grid (32 q-tiles, 8 heads, 4 splits) =
// 1024 blocks; LDS 27.6 KB -> 4-5 resident blocks/CU. No-max softmax (q
// pre-scaled by 1/8 in qkv GEMM). Partials: l -> pm, unnormalized O (bf16)
// -> po; 4-way merge fused into attn-out GEMM.
__global__ __launch_bounds__(256) void flash_attn9(
    const unsigned short* __restrict__ qkv, float* __restrict__ pm,
    unsigned short* __restrict__ po) {
  __shared__ __align__(16) unsigned short Ks[64][72];
  __shared__ __align__(16) unsigned short Vt[64][72];
  __shared__ __align__(16) unsigned short Ps[64][72];
  const int qt = blockIdx.x, h = blockIdx.y, sp = blockIdx.z;
  const int tid = threadIdx.x;
  const int wid = tid >> 6, lane = tid & 63;
  const int ln = lane & 15, quad = lane >> 4;
  const int wq0 = wid * 16;

  bf16x8 aq[2];
  {
    const unsigned short* qp =
        qkv + (size_t)(qt * 64 + wq0 + ln) * 1536 + h * 64 + quad * 8;
    aq[0] = *(const bf16x8*)qp;
    aq[1] = *(const bf16x8*)(qp + 32);
  }
  const bf16x8 ones = {0x3F80, 0x3F80, 0x3F80, 0x3F80,
                       0x3F80, 0x3F80, 0x3F80, 0x3F80};  // bf16 1.0 x8

  const int key = tid >> 2, seg = tid & 3;  // K staging
  bf16x8 rk0, rk1;
  unsigned short tv[16];

  auto load_kv = [&](int t) {
    const int g = sp * 8 + t;
    const unsigned short* kr =
        qkv + (size_t)(g * 64 + key) * 1536 + 512 + h * 64 + seg * 16;
    rk0 = *(const bf16x8*)kr;
    rk1 = *(const bf16x8*)(kr + 8);
#pragma unroll
    for (int j = 0; j < 16; ++j)
      tv[j] = qkv[(size_t)(g * 64 + wid * 16 + j) * 1536 + 1024 + h * 64 + lane];
  };
  auto store_kv = [&]() {
    *(bf16x8*)&Ks[key][seg * 16] = rk0;
    *(bf16x8*)&Ks[key][seg * 16 + 8] = rk1;
    *(bf16x8*)&Vt[lane][wid * 16] = *(const bf16x8*)&tv[0];
    *(bf16x8*)&Vt[lane][wid * 16 + 8] = *(const bf16x8*)&tv[8];
  };

  f32x4 acc_l = (f32x4){0.f, 0.f, 0.f, 0.f};
  f32x4 acc_o[4];
#pragma unroll
  for (int nt = 0; nt < 4; ++nt) acc_o[nt] = (f32x4){0.f, 0.f, 0.f, 0.f};

  load_kv(0);
  store_kv();
  __syncthreads();

#pragma unroll 1
  for (int t = 0; t < 8; ++t) {
    if (t + 1 < 8) load_kv(t + 1);  // global latency overlaps compute

    f32x4 s_acc[4];
#pragma unroll
    for (int nt = 0; nt < 4; ++nt) s_acc[nt] = (f32x4){0.f, 0.f, 0.f, 0.f};
#pragma unroll
    for (int nt = 0; nt < 4; ++nt) {
      bf16x8 kf0 = *(const bf16x8*)&Ks[nt * 16 + ln][quad * 8];
      bf16x8 kf1 = *(const bf16x8*)&Ks[nt * 16 + ln][32 + quad * 8];
      s_acc[nt] = __builtin_amdgcn_mfma_f32_16x16x32_bf16(aq[0], kf0, s_acc[nt], 0, 0, 0);
      s_acc[nt] = __builtin_amdgcn_mfma_f32_16x16x32_bf16(aq[1], kf1, s_acc[nt], 0, 0, 0);
    }

    // p = exp(s) (q pre-scaled); P -> LDS (wave-local rows)
#pragma unroll
    for (int nt = 0; nt < 4; ++nt) {
#pragma unroll
      for (int r = 0; r < 4; ++r) {
        float p = __expf(s_acc[nt][r]);
        Ps[wq0 + quad * 4 + r][nt * 16 + ln] = f2b(p);
      }
    }

#pragma unroll
    for (int kc = 0; kc < 2; ++kc) {
      bf16x8 pf = *(const bf16x8*)&Ps[wq0 + ln][kc * 32 + quad * 8];
      acc_l = __builtin_amdgcn_mfma_f32_16x16x32_bf16(pf, ones, acc_l, 0, 0, 0);
#pragma unroll
      for (int nt = 0; nt < 4; ++nt) {
        bf16x8 vf = *(const bf16x8*)&Vt[nt * 16 + ln][kc * 32 + quad * 8];
        acc_o[nt] = __builtin_amdgcn_mfma_f32_16x16x32_bf16(pf, vf, acc_o[nt], 0, 0, 0);
      }
    }
    __syncthreads();  // all reads of Ks/Vt complete before overwrite
    if (t + 1 < 8) {
      store_kv();
      __syncthreads();
    }
  }

  // epilogue: l comes straight out of acc_l (all 16 cols equal); no shuffles
  const size_t base = (size_t)((sp * 8 + h) * 2048 + qt * 64);
#pragma unroll
  for (int r = 0; r < 4; ++r) {
    const size_t row = base + wq0 + quad * 4 + r;
    if (ln == 0) pm[row] = acc_l[r];
#pragma unroll
    for (int nt = 0; nt < 4; ++nt)
      po[row * 64 + nt * 16 + ln] = f2b(acc_o[nt][r]);
  }
}

// ============ Row-wise kernels (one wave per row of 2048) ==================
__global__ __launch_bounds__(256) void inorm512(float* __restrict__ dst,
                                                unsigned short* __restrict__ dstb,
                                                const float* __restrict__ src) {
  const int row = blockIdx.x * 4 + (threadIdx.x >> 6);
  const int lane = threadIdx.x & 63;
  const float4* s = (const float4*)(src + (size_t)row * 512);
  float4 a = s[lane], b = s[lane + 64];
  float sum = a.x + a.y + a.z + a.w + b.x + b.y + b.z + b.w;
  float mean = wave_sum(sum) * (1.f / 512.f);
  float vs = (a.x - mean) * (a.x - mean) + (a.y - mean) * (a.y - mean) +
             (a.z - mean) * (a.z - mean) + (a.w - mean) * (a.w - mean) +
             (b.x - mean) * (b.x - mean) + (b.y - mean) * (b.y - mean) +
             (b.z - mean) * (b.z - mean) + (b.w - mean) * (b.w - mean);
  float rs = rsqrtf(wave_sum(vs) * (1.f / 512.f) + EPS);
  float4 oa, obv;
  oa.x = (a.x - mean) * rs; oa.y = (a.y - mean) * rs;
  oa.z = (a.z - mean) * rs; oa.w = (a.w - mean) * rs;
  obv.x = (b.x - mean) * rs; obv.y = (b.y - mean) * rs;
  obv.z = (b.z - mean) * rs; obv.w = (b.w - mean) * rs;
  float4* d = (float4*)(dst + (size_t)row * 512);
  d[lane] = oa; d[lane + 64] = obv;
  unsigned short* db = dstb + (size_t)row * 512;
  *(ushort2*)&db[lane * 4] = pk2b(oa.x, oa.y);
  *(ushort2*)&db[lane * 4 + 2] = pk2b(oa.z, oa.w);
  *(ushort2*)&db[256 + lane * 4] = pk2b(obv.x, obv.y);
  *(ushort2*)&db[256 + lane * 4 + 2] = pk2b(obv.z, obv.w);
}

// LN over rows of src (already residual-summed); writes f32 + bf16
__global__ __launch_bounds__(256) void ln_res2(float* __restrict__ dst,
                                               unsigned short* __restrict__ dstb,
                                               const float* __restrict__ src,
                                               const float* __restrict__ w,
                                               const float* __restrict__ bb) {
  const int row = blockIdx.x * 4 + (threadIdx.x >> 6);
  const int lane = threadIdx.x & 63;
  const float4* xs = (const float4*)(src + (size_t)row * 512);
  float4 a = xs[lane], b = xs[lane + 64];
  float sum = a.x + a.y + a.z + a.w + b.x + b.y + b.z + b.w;
  float mean = wave_sum(sum) * (1.f / 512.f);
  float vs = (a.x - mean) * (a.x - mean) + (a.y - mean) * (a.y - mean) +
             (a.z - mean) * (a.z - mean) + (a.w - mean) * (a.w - mean) +
             (b.x - mean) * (b.x - mean) + (b.y - mean) * (b.y - mean) +
             (b.z - mean) * (b.z - mean) + (b.w - mean) * (b.w - mean);
  float rs = rsqrtf(wave_sum(vs) * (1.f / 512.f) + EPS);
  float4 wa = ((const float4*)w)[lane], wb = ((const float4*)w)[lane + 64];
  float4 ba = ((const float4*)bb)[lane], bbv = ((const float4*)bb)[lane + 64];
  float4 oa, ob2;
  oa.x = (a.x - mean) * rs * wa.x + ba.x; oa.y = (a.y - mean) * rs * wa.y + ba.y;
  oa.z = (a.z - mean) * rs * wa.z + ba.z; oa.w = (a.w - mean) * rs * wa.w + ba.w;
  ob2.x = (b.x - mean) * rs * wb.x + bbv.x; ob2.y = (b.y - mean) * rs * wb.y + bbv.y;
  ob2.z = (b.z - mean) * rs * wb.z + bbv.z; ob2.w = (b.w - mean) * rs * wb.w + bbv.w;
  float4* d = (float4*)(dst + (size_t)row * 512);
  d[lane] = oa; d[lane + 64] = ob2;
  unsigned short* dbp = dstb + (size_t)row * 512;
  *(ushort2*)&dbp[lane * 4] = pk2b(oa.x, oa.y);
  *(ushort2*)&dbp[lane * 4 + 2] = pk2b(oa.z, oa.w);
  *(ushort2*)&dbp[256 + lane * 4] = pk2b(ob2.x, ob2.y);
  *(ushort2*)&dbp[256 + lane * 4 + 2] = pk2b(ob2.z, ob2.w);
}

__global__ __launch_bounds__(256) void add_inorm(float* __restrict__ feat,
                                                 unsigned short* __restrict__ featb,
                                                 const float* __restrict__ feat0) {
  const int row = blockIdx.x * 4 + (threadIdx.x >> 6);
  const int lane = threadIdx.x & 63;
  float4* f = (float4*)(feat + (size_t)row * 512);
  const float4* f0 = (const float4*)(feat0 + (size_t)row * 512);
  float4 a = f[lane], b = f[lane + 64];
  float sum = a.x + a.y + a.z + a.w + b.x + b.y + b.z + b.w;
  float mean = wave_sum(sum) * (1.f / 512.f);
  float vs = (a.x - mean) * (a.x - mean) + (a.y - mean) * (a.y - mean) +
             (a.z - mean) * (a.z - mean) + (a.w - mean) * (a.w - mean) +
             (b.x - mean) * (b.x - mean) + (b.y - mean) * (b.y - mean) +
             (b.z - mean) * (b.z - mean) + (b.w - mean) * (b.w - mean);
  float rs = rsqrtf(wave_sum(vs) * (1.f / 512.f) + EPS);
  float4 za = f0[lane], zb = f0[lane + 64];
  float4 oa, ob2;
  oa.x = za.x + (a.x - mean) * rs; oa.y = za.y + (a.y - mean) * rs;
  oa.z = za.z + (a.z - mean) * rs; oa.w = za.w + (a.w - mean) * rs;
  ob2.x = zb.x + (b.x - mean) * rs; ob2.y = zb.y + (b.y - mean) * rs;
  ob2.z = zb.z + (b.z - mean) * rs; ob2.w = zb.w + (b.w - mean) * rs;
  f[lane] = oa; f[lane + 64] = ob2;
  unsigned short* dbp = featb + (size_t)row * 512;
  *(ushort2*)&dbp[lane * 4] = pk2b(oa.x, oa.y);
  *(ushort2*)&dbp[lane * 4 + 2] = pk2b(oa.z, oa.w);
  *(ushort2*)&dbp[256 + lane * 4] = pk2b(ob2.x, ob2.y);
  *(ushort2*)&dbp[256 + lane * 4 + 2] = pk2b(ob2.z, ob2.w);
}

// dist with fused inorm128: one wave per row
__global__ __launch_bounds__(256) void dist2(const float* __restrict__ fq,
                                             const float* __restrict__ hi,
                                             const float* __restrict__ ne,
                                             float* __restrict__ out) {
  const int row = blockIdx.x * 4 + (threadIdx.x >> 6);
  const int lane = threadIdx.x & 63;
  float f0 = fq[(size_t)row * 128 + lane];
  float f1 = fq[(size_t)row * 128 + 64 + lane];
  float mean = wave_sum(f0 + f1) * (1.f / 128.f);
  float vs = (f0 - mean) * (f0 - mean) + (f1 - mean) * (f1 - mean);
  float rs = rsqrtf(wave_sum(vs) * (1.f / 128.f) + EPS);
  f0 = (f0 - mean) * rs;
  f1 = (f1 - mean) * rs;
  float mp = 1e30f, mn = 1e30f;
  for (int p = 0; p < 40; ++p) {
    float h0 = hi[p * 128 + lane], h1 = hi[p * 128 + 64 + lane];
    float d0 = f0 - h0, d1 = f1 - h1;
    float d2 = wave_sum(d0 * d0 + d1 * d1);
    mp = fminf(mp, d2);
    float n0 = ne[p * 128 + lane], n1 = ne[p * 128 + 64 + lane];
    d0 = f0 - n0; d1 = f1 - n1;
    d2 = wave_sum(d0 * d0 + d1 * d1);
    mn = fminf(mn, d2);
  }
  if (lane == 0) {
    out[row * 2 + 0] = -sqrtf(mn);
    out[row * 2 + 1] = -sqrtf(mp);
  }
}

extern "C" void kernel_launch(void* const* d_in, const int* in_sizes, int n_in,
                              void* d_out, int out_size, void* d_ws, size_t ws_size,
                              hipStream_t stream) {
  const float* x        = (const float*)d_in[0];
  const float* reduce_w = (const float*)d_in[1];
  const float* reduce_b = (const float*)d_in[2];
  const float* in_w     = (const float*)d_in[3];
  const float* in_b     = (const float*)d_in[4];
  const float* out_w    = (const float*)d_in[5];
  const float* out_b    = (const float*)d_in[6];
  const float* ff1_w    = (const float*)d_in[7];
  const float* ff1_b    = (const float*)d_in[8];
  const float* ff2_w    = (const float*)d_in[9];
  const float* ff2_b    = (const float*)d_in[10];
  const float* ln1_w    = (const float*)d_in[11];
  const float* ln1_b    = (const float*)d_in[12];
  const float* ln2_w    = (const float*)d_in[13];
  const float* ln2_b    = (const float*)d_in[14];
  const float* mlp_w1   = (const float*)d_in[15];
  const float* mlp_b1   = (const float*)d_in[16];
  const float* mlp_w2   = (const float*)d_in[17];
  const float* mlp_b2   = (const float*)d_in[18];
  const float* mlp_w3   = (const float*)d_in[19];
  const float* mlp_b3   = (const float*)d_in[20];
  const float* hi       = (const float*)d_in[21];
  const float* ne       = (const float*)d_in[22];
  float* out = (float*)d_out;
  float* ws = (float*)d_ws;

  const size_t MD = (size_t)2048 * 512;  // 1M elems
  float* feat0_f = ws;                // MD
  float* feat_f  = ws + MD;           // MD
  float* tmp_f   = ws + 2 * MD;       // MD
  float* pm      = ws + 3 * MD;       // 4*8*2048 = 65536 f32
  unsigned short* u = (unsigned short*)(ws + 3 * MD + 65536);
  unsigned short* qkv_b   = u;            // 3*MD
  unsigned short* feat0_b = u + 3 * MD;   // MD
  unsigned short* feat_b  = u + 4 * MD;   // MD
  unsigned short* relu_b  = u + 5 * MD;   // MD
  unsigned short* po_b    = u + 6 * MD;   // 4*8*2048*64 = 4*MD
  unsigned short* relu2_b = qkv_b;        // alias: attention done by then
  float* featq_f = tmp_f;

  // bf16 weight region
  unsigned short* wb = u + 10 * MD;
  unsigned short* reduce_wb = wb;                   // 393216
  unsigned short* in_wb     = wb + 393216;          // 2359296
  unsigned short* out_wb    = in_wb + 2359296;      // 786432
  unsigned short* ff1_wb    = out_wb + 786432;      // 786432
  unsigned short* ff2_wb    = ff1_wb + 786432;      // 786432
  unsigned short* mlp_w1b   = ff2_wb + 786432;      // 262144
  unsigned short* mlp_w2b   = mlp_w1b + 262144;     // 262144
  unsigned short* mlp_w3b   = mlp_w2b + 262144;     // 65536

  dim3 blk(256);
  WConvArgs wa;
  wa.src[0] = reduce_w; wa.dst[0] = reduce_wb; wa.n[0] = 393216;
  wa.src[1] = in_w;     wa.dst[1] = in_wb;     wa.n[1] = 2359296;
  wa.src[2] = out_w;    wa.dst[2] = out_wb;    wa.n[2] = 786432;
  wa.src[3] = ff1_w;    wa.dst[3] = ff1_wb;    wa.n[3] = 786432;
  wa.src[4] = ff2_w;    wa.dst[4] = ff2_wb;    wa.n[4] = 786432;
  wa.src[5] = mlp_w1;   wa.dst[5] = mlp_w1b;   wa.n[5] = 262144;
  wa.src[6] = mlp_w2;   wa.dst[6] = mlp_w2b;   wa.n[6] = 262144;
  wa.src[7] = mlp_w3;   wa.dst[7] = mlp_w3b;   wa.n[7] = 65536;
  conv_w<<<dim3(2304, 8), blk, 0, stream>>>(wa);

  gemm32<0, 1, 1, 0, 0, 0, 0><<<dim3(64, 8), blk, 0, stream>>>(
      x, nullptr, reduce_wb, reduce_b, nullptr, feat0_f, nullptr, 2048, 512, 768);
  inorm512<<<512, blk, 0, stream>>>(feat0_f, feat0_b, feat0_f);

  for (int i = 0; i < 3; ++i) {
    const float* fin_f = (i == 0) ? feat0_f : feat_f;
    const unsigned short* fin_b = (i == 0) ? feat0_b : feat_b;
    gemm32<0, 0, 0, 1, 0, 0, 1><<<dim3(64, 24), blk, 0, stream>>>(
        fin_b, nullptr, in_wb + (size_t)i * 1536 * 512, in_b + i * 1536,
        nullptr, nullptr, qkv_b, 2048, 1536, 512);
    flash_attn9<<<dim3(32, 8, 4), blk, 0, stream>>>(qkv_b, pm, po_b);
    gemm32<0, 0, 1, 0, 1, 1, 0><<<dim3(64, 8), blk, 0, stream>>>(
        po_b, pm, out_wb + (size_t)i * 512 * 512, out_b + i * 512,
        fin_f, tmp_f, nullptr, 2048, 512, 512);
    ln_res2<<<512, blk, 0, stream>>>(feat_f, feat_b, tmp_f,
                                     ln1_w + i * 512, ln1_b + i * 512);
    gemm32<1, 0, 0, 1, 0, 0, 0><<<dim3(64, 8), blk, 0, stream>>>(
        feat_b, nullptr, ff1_wb + (size_t)i * 512 * 512, ff1_b + i * 512,
        nullptr, nullptr, relu_b, 2048, 512, 512);
    gemm32<0, 0, 1, 0, 0, 1, 0><<<dim3(64, 8), blk, 0, stream>>>(
        relu_b, nullptr, ff2_wb + (size_t)i * 512 * 512, ff2_b + i * 512,
        feat_f, tmp_f, nullptr, 2048, 512, 512);
    ln_res2<<<512, blk, 0, stream>>>(feat_f, feat_b, tmp_f,
                                     ln2_w + i * 512, ln2_b + i * 512);
  }

  add_inorm<<<512, blk, 0, stream>>>(feat_f, feat_b, feat0_f);
  gemm32<1, 0, 0, 1, 0, 0, 0><<<dim3(64, 8), blk, 0, stream>>>(
      feat_b, nullptr, mlp_w1b, mlp_b1, nullptr, nullptr, relu_b, 2048, 512, 512);
  gemm32<1, 0, 0, 1, 0, 0, 0><<<dim3(64, 8), blk, 0, stream>>>(
      relu_b, nullptr, mlp_w2b, mlp_b2, nullptr, nullptr, relu2_b, 2048, 512, 512);
  gemm32<0, 0, 1, 0, 0, 0, 0><<<dim3(64, 2), blk, 0, stream>>>(
      relu2_b, nullptr, mlp_w3b, mlp_b3, nullptr, featq_f, nullptr, 2048, 128, 512);
  dist2<<<512, blk, 0, stream>>>(featq_f, hi, ne, out);
}